// Round 2
// baseline (965.765 us; speedup 1.0000x reference)
//
#include <hip/hip_runtime.h>
#include <hip/hip_bf16.h>
#include <stdint.h>

// ---- problem constants -----------------------------------------------------
#define B_    8
#define T_    256
#define U_    64
#define JD    512              // joint dim (N of projections, K of gemm3)
#define VD    1024             // vocab
#define ROWS  (B_*T_*U_)       // 131072 joint rows
#define MTOT  (B_*T_)          // 2048 enc rows
#define UROWS (B_*U_)          // 512 pred rows

typedef __attribute__((ext_vector_type(8))) short short8;   // 8 bf16 = 4 VGPR
typedef __attribute__((ext_vector_type(4))) float f32x4;

// ---- helpers ---------------------------------------------------------------
__device__ __forceinline__ unsigned short f2bf(float f) {   // RNE
  unsigned u = __float_as_uint(f);
  u += 0x7fffu + ((u >> 16) & 1u);
  return (unsigned short)(u >> 16);
}
// tanh(x) = 1 - 2/(exp2(2*log2e*x)+1); handles +-inf gracefully (-> +-1)
__device__ __forceinline__ float fast_tanh(float x) {
  float e = __builtin_amdgcn_exp2f(x * 2.8853900817779268f);
  return 1.0f - 2.0f * __builtin_amdgcn_rcpf(e + 1.0f);
}

// ---- W pack: row-major fp32 [K][N] -> bf16 B-fragment layout ---------------
// frag(nt16, kc): lane l holds B[k=kc*32+(l>>4)*8+j][n=nt16*16+(l&15)], j=0..7
// dst short index: (((nt16*(K/32)+kc)*64 + lane)*8 + j)
__global__ void __launch_bounds__(256) k_pack_w(
    const float* __restrict__ W, unsigned short* __restrict__ dst,
    int K, int N) {
  int t = blockIdx.x * blockDim.x + threadIdx.x;
  int total = (K * N) >> 3;
  if (t >= total) return;
  int lane = t & 63;
  int rest = t >> 6;
  int kch  = K >> 5;
  int kc   = rest % kch;
  int nt   = rest / kch;
  int krow = (kc << 5) + ((lane >> 4) << 3);
  int col  = (nt << 4) + (lane & 15);
  unsigned short v[8];
#pragma unroll
  for (int j = 0; j < 8; ++j) v[j] = f2bf(W[(size_t)(krow + j) * N + col]);
  uint4 o;
  o.x = v[0] | ((unsigned)v[1] << 16);
  o.y = v[2] | ((unsigned)v[3] << 16);
  o.z = v[4] | ((unsigned)v[5] << 16);
  o.w = v[6] | ((unsigned)v[7] << 16);
  *(uint4*)(dst + ((size_t)t << 3)) = o;
}

// ---- projection GEMM: C[M][N] fp32 = A_fp32[M][K] @ Bpacked_bf16 + bias ----
// wave-tile 16 rows x 64 cols, no LDS
__global__ void __launch_bounds__(256) k_proj(
    const float* __restrict__ A, const unsigned short* __restrict__ Bp,
    const float* __restrict__ bias, float* __restrict__ C,
    int M, int K, int N) {
  int w    = (blockIdx.x * blockDim.x + threadIdx.x) >> 6;
  int lane = threadIdx.x & 63;
  int nw   = N >> 6;                      // waves along N
  int wm   = w / nw, wn = w % nw;
  int m0   = wm << 4, n0 = wn << 6;
  if (m0 >= M) return;
  int kch = K >> 5;
  int q = lane >> 4, c = lane & 15;
  f32x4 acc[4] = {f32x4{0,0,0,0}, f32x4{0,0,0,0}, f32x4{0,0,0,0}, f32x4{0,0,0,0}};
  const float* arow = A + (size_t)(m0 + c) * K + (q << 3);
  for (int kc = 0; kc < kch; ++kc) {
    float4 a0 = *(const float4*)(arow + (kc << 5));
    float4 a1 = *(const float4*)(arow + (kc << 5) + 4);
    short8 a;
    a[0] = (short)f2bf(a0.x); a[1] = (short)f2bf(a0.y);
    a[2] = (short)f2bf(a0.z); a[3] = (short)f2bf(a0.w);
    a[4] = (short)f2bf(a1.x); a[5] = (short)f2bf(a1.y);
    a[6] = (short)f2bf(a1.z); a[7] = (short)f2bf(a1.w);
#pragma unroll
    for (int j = 0; j < 4; ++j) {
      size_t nt16 = (size_t)((n0 >> 4) + j);
      short8 b = *(const short8*)(Bp + (((nt16 * kch + kc) << 6) + lane) * 8);
      acc[j] = __builtin_amdgcn_mfma_f32_16x16x32_bf16(a, b, acc[j], 0, 0, 0);
    }
  }
#pragma unroll
  for (int j = 0; j < 4; ++j) {
    int col = n0 + (j << 4) + c;
    float bv = bias[col];
#pragma unroll
    for (int r = 0; r < 4; ++r) {
      int row = m0 + (q << 2) + r;          // C/D: row=(lane>>4)*4+reg
      C[(size_t)row * N + col] = acc[j][r] + bv;
    }
  }
}

// ---- tanh + pack A into bf16 A-fragment layout -----------------------------
// A-frag(rb, kc): lane l holds A[m=rb*16+(l&15)][k=kc*32+(l>>4)*8+j]
// flat short idx: ((rb*16+kc)*64 + lane)*8 + j;  thread t = ((rb*16+kc)*64+lane)
__global__ void __launch_bounds__(256) k_tanh_pack(
    const float* __restrict__ enc_p, const float* __restrict__ pred_p,
    unsigned short* __restrict__ Ap) {
  int t    = blockIdx.x * blockDim.x + threadIdx.x;   // 8,388,608 threads
  int lane = t & 63;
  int F    = t >> 6;                 // rb*16 + kc
  int rb   = F >> 4, kc = F & 15;
  int r    = (rb << 4) + (lane & 15);            // global joint row
  int k0   = (kc << 5) + ((lane >> 4) << 3);
  const float* ep = enc_p  + ((size_t)(r >> 6) << 9) + k0;                       // (b*T+t)*512
  const float* pp = pred_p + ((size_t)(((r >> 14) << 6) + (r & 63)) << 9) + k0;  // (b*U+u)*512
  float4 e0 = *(const float4*)ep, e1 = *(const float4*)(ep + 4);
  float4 p0 = *(const float4*)pp, p1 = *(const float4*)(pp + 4);
  unsigned short v[8];
  v[0] = f2bf(fast_tanh(e0.x + p0.x));
  v[1] = f2bf(fast_tanh(e0.y + p0.y));
  v[2] = f2bf(fast_tanh(e0.z + p0.z));
  v[3] = f2bf(fast_tanh(e0.w + p0.w));
  v[4] = f2bf(fast_tanh(e1.x + p1.x));
  v[5] = f2bf(fast_tanh(e1.y + p1.y));
  v[6] = f2bf(fast_tanh(e1.z + p1.z));
  v[7] = f2bf(fast_tanh(e1.w + p1.w));
  uint4 o;
  o.x = v[0] | ((unsigned)v[1] << 16);
  o.y = v[2] | ((unsigned)v[3] << 16);
  o.z = v[4] | ((unsigned)v[5] << 16);
  o.w = v[6] | ((unsigned)v[7] << 16);
  *(uint4*)(Ap + ((size_t)t << 3)) = o;
}

// ---- main GEMM: out_fp32[ROWS][VD] = Ap @ Wjnt_p + b_joint -----------------
// barrier-free: block = 4 waves in 2x2, each wave 64x64; all frags from global
__global__ void __launch_bounds__(256) k_gemm3(
    const unsigned short* __restrict__ Ap, const unsigned short* __restrict__ Bp,
    const float* __restrict__ bias, float* __restrict__ out) {
  int bid  = blockIdx.x;
  int nt   = bid & 7;                 // n fastest -> 8 consecutive blocks share A stripe
  int mt   = bid >> 3;
  int w    = threadIdx.x >> 6, lane = threadIdx.x & 63;
  int wm   = w >> 1, wn = w & 1;
  int rb0  = (mt << 3) + (wm << 2);   // base row-block (16-row units)
  int nt0  = (nt << 3) + (wn << 2);   // base col-tile (16-col units)
  const short8* a8 = (const short8*)Ap;
  const short8* b8 = (const short8*)Bp;

  f32x4 acc[4][4];
#pragma unroll
  for (int i = 0; i < 4; ++i)
#pragma unroll
    for (int j = 0; j < 4; ++j) acc[i][j] = f32x4{0, 0, 0, 0};

  short8 a[4], b[4], an[4], bn[4];
#pragma unroll
  for (int i = 0; i < 4; ++i) {
    a[i] = a8[(((size_t)(rb0 + i) * 16 + 0) << 6) + lane];
    b[i] = b8[(((size_t)(nt0 + i) * 16 + 0) << 6) + lane];
  }
#pragma unroll
  for (int kc = 0; kc < 16; ++kc) {
    if (kc < 15) {
#pragma unroll
      for (int i = 0; i < 4; ++i) {
        an[i] = a8[(((size_t)(rb0 + i) * 16 + kc + 1) << 6) + lane];
        bn[i] = b8[(((size_t)(nt0 + i) * 16 + kc + 1) << 6) + lane];
      }
    }
#pragma unroll
    for (int i = 0; i < 4; ++i)
#pragma unroll
      for (int j = 0; j < 4; ++j)
        acc[i][j] = __builtin_amdgcn_mfma_f32_16x16x32_bf16(a[i], b[j], acc[i][j], 0, 0, 0);
#pragma unroll
    for (int i = 0; i < 4; ++i) { a[i] = an[i]; b[i] = bn[i]; }
  }

  int q = lane >> 4, c = lane & 15;
#pragma unroll
  for (int j = 0; j < 4; ++j) {
    int col = ((nt0 + j) << 4) + c;
    float bv = bias[col];
#pragma unroll
    for (int i = 0; i < 4; ++i) {
      int row = ((rb0 + i) << 4) + (q << 2);
      size_t o = ((size_t)row << 10) + col;
#pragma unroll
      for (int r = 0; r < 4; ++r)
        out[o + ((size_t)r << 10)] = acc[i][j][r] + bv;
    }
  }
}

// ---- fallbacks (only if ws_size is too small for A_pack) -------------------
__global__ void __launch_bounds__(256) k_proj_naive(
    const float* __restrict__ A, const float* __restrict__ W,
    const float* __restrict__ bias, float* __restrict__ C,
    int M, int K, int N) {
  int t = blockIdx.x * blockDim.x + threadIdx.x;
  if (t >= M * N) return;
  int row = t / N, col = t % N;
  float s = bias[col];
  for (int k = 0; k < K; ++k)
    s += A[(size_t)row * K + k] * W[(size_t)k * N + col];
  C[t] = s;
}
__global__ void __launch_bounds__(256) k_joint_naive(
    const float* __restrict__ enc_p, const float* __restrict__ pred_p,
    const float* __restrict__ Wj, const float* __restrict__ bj,
    float* __restrict__ out) {
  __shared__ float jrow[JD];
  int gr = blockIdx.x;
  int bt = gr >> 6;
  int bu = ((gr >> 14) << 6) + (gr & 63);
  for (int k = threadIdx.x; k < JD; k += 256)
    jrow[k] = fast_tanh(enc_p[(size_t)bt * JD + k] + pred_p[(size_t)bu * JD + k]);
  __syncthreads();
  int v0 = threadIdx.x * 4;
  float s0 = bj[v0], s1 = bj[v0 + 1], s2 = bj[v0 + 2], s3 = bj[v0 + 3];
  for (int k = 0; k < JD; ++k) {
    float jv = jrow[k];
    const float* wr = Wj + (size_t)k * VD + v0;
    s0 += jv * wr[0];
    s1 += jv * wr[1];
    s2 += jv * wr[2];
    s3 += jv * wr[3];
  }
  size_t o = ((size_t)gr << 10) + v0;
  out[o] = s0; out[o + 1] = s1; out[o + 2] = s2; out[o + 3] = s3;
}

// ---- host ------------------------------------------------------------------
extern "C" void kernel_launch(void* const* d_in, const int* in_sizes, int n_in,
                              void* d_out, int out_size, void* d_ws, size_t ws_size,
                              hipStream_t stream) {
  const float* enc_out  = (const float*)d_in[0];
  const float* pred_out = (const float*)d_in[1];
  const float* W_enc    = (const float*)d_in[2];
  const float* b_enc    = (const float*)d_in[3];
  const float* W_pred   = (const float*)d_in[4];
  const float* b_pred   = (const float*)d_in[5];
  const float* W_joint  = (const float*)d_in[6];
  const float* b_joint  = (const float*)d_in[7];
  float* out = (float*)d_out;

  char* ws = (char*)d_ws;
  size_t off = 0;
  auto alloc = [&](size_t bytes) -> char* {
    char* p = ws + off;
    off += (bytes + 255) & ~(size_t)255;
    return p;
  };
  float* enc_p  = (float*)alloc((size_t)MTOT * JD * 4);    // 4 MB
  float* pred_p = (float*)alloc((size_t)UROWS * JD * 4);   // 1 MB
  size_t small_need = off;
  unsigned short* Wenc_p  = (unsigned short*)alloc((size_t)512 * 512 * 2);
  unsigned short* Wpred_p = (unsigned short*)alloc((size_t)640 * 512 * 2);
  unsigned short* Wjnt_p  = (unsigned short*)alloc((size_t)512 * 1024 * 2);
  unsigned short* Ap      = (unsigned short*)alloc((size_t)ROWS * JD * 2);  // 128 MiB
  size_t big_need = off;

  if (ws_size >= big_need) {
    k_pack_w<<<(512 * 512 / 8) / 256, 256, 0, stream>>>(W_enc, Wenc_p, 512, 512);
    k_pack_w<<<(640 * 512 / 8) / 256, 256, 0, stream>>>(W_pred, Wpred_p, 640, 512);
    k_pack_w<<<(512 * 1024 / 8) / 256, 256, 0, stream>>>(W_joint, Wjnt_p, 512, 1024);
    k_proj<<<(MTOT / 16) * (JD / 64) / 4, 256, 0, stream>>>(enc_out, Wenc_p, b_enc, enc_p, MTOT, 512, JD);
    k_proj<<<(UROWS / 16) * (JD / 64) / 4, 256, 0, stream>>>(pred_out, Wpred_p, b_pred, pred_p, UROWS, 640, JD);
    k_tanh_pack<<<((size_t)ROWS * JD / 8) / 256, 256, 0, stream>>>(enc_p, pred_p, Ap);
    k_gemm3<<<(ROWS / 128) * (VD / 128), 256, 0, stream>>>(Ap, Wjnt_p, b_joint, out);
  } else if (ws_size >= small_need) {
    k_proj_naive<<<(MTOT * JD + 255) / 256, 256, 0, stream>>>(enc_out, W_enc, b_enc, enc_p, MTOT, 512, JD);
    k_proj_naive<<<(UROWS * JD + 255) / 256, 256, 0, stream>>>(pred_out, W_pred, b_pred, pred_p, UROWS, 640, JD);
    k_joint_naive<<<ROWS, 256, 0, stream>>>(enc_p, pred_p, W_joint, b_joint, out);
  }
  (void)in_sizes; (void)n_in; (void)out_size;
}